// Round 4
// baseline (229.861 us; speedup 1.0000x reference)
//
#include <hip/hip_runtime.h>
#include <stdint.h>

typedef float f32x4 __attribute__((ext_vector_type(4)));
typedef __bf16 bf16x8 __attribute__((ext_vector_type(8)));
typedef unsigned short ushort4v __attribute__((ext_vector_type(4)));

#define DIM 4608
#define BK 32
#define NT 16
#define WS_L_BYTES (16 * 4 * 512 * 16)  // 512 KiB per l: 16 tiles x [grp4][col512][8 bf16]

// Phase boundary: wait own LDS ops, raw barrier — NO vmcnt drain (prefetch stays in flight).
#define BAR()                                    \
  do {                                           \
    __builtin_amdgcn_sched_barrier(0);           \
    asm volatile("s_waitcnt lgkmcnt(0)");        \
    __builtin_amdgcn_s_barrier();                \
    __builtin_amdgcn_sched_barrier(0);           \
  } while (0)

// ---------------- prepack: W (fp32) -> ws (bf16, c folded, B-fragment order) ----------------
__global__ __launch_bounds__(256) void prepack(const float* __restrict__ W0,
                                               const float* __restrict__ W1,
                                               const float* __restrict__ W2,
                                               char* __restrict__ ws) {
  int gid = blockIdx.x * 256 + threadIdx.x;  // 3*16*4*512 = 98304 threads
  int col = gid & 511;
  int rest = gid >> 9;
  int grp = rest & 3;
  rest >>= 2;
  int t = rest & 15;
  int l = rest >> 4;
  const float* W = (l == 0) ? W0 : ((l == 1) ? W1 : W2);
  const float c = 0.044194173824159216f;  // 1/sqrt(512) path normalization
  union {
    bf16x8 v;
    uint4 u;
  } pk;
#pragma unroll
  for (int jj = 0; jj < 8; ++jj) {
    float v = W[(t * 32 + grp * 8 + jj) * 512 + col] * c;
    pk.v[jj] = (__bf16)v;
  }
  *(uint4*)(ws + (size_t)l * WS_L_BYTES + ((size_t)((t * 4 + grp) * 512 + col) << 4)) = pk.u;
}

// ---------------- fused per-l GEMM body ----------------
// Block: BZ z-samples x 256 w-cols (col-half cb). 8 waves; wave = 32 cols (2 ct-tiles).
// A double-buffered in LDS (fragment order); B from L2-resident ws into regs.
// lb: local block id; lb>>1 = z-chunk, lb&1 = col half (adjacent pairs -> L3 reuse of x1).
template <int D, int BZ, int OFF>
__device__ __forceinline__ void gemm_body(int lb, const float* __restrict__ x1,
                                          const float* __restrict__ x2,
                                          const char* __restrict__ wsl,
                                          float* __restrict__ out,
                                          char* __restrict__ smem) {
  constexpr int BM = BZ * D;             // rows (z,i) per block
  constexpr int R = BM / 16;             // 16-row tiles
  constexpr int ABYTES = BM * 64;        // bf16 A tile bytes (BM * BK * 2)
  constexpr int CNT = BZ * 8 * D;        // float4 loads per A tile
  constexpr int PF = (CNT + 511) / 512;  // load slots per thread

  const int tid = threadIdx.x;
  const int z0 = (lb >> 1) * BZ;
  const int cb = (lb & 1) * 256;
  const float* xbase = x1 + (size_t)z0 * DIM + OFF;

  const int lane = tid & 63;
  const int wave = tid >> 6;
  const int llo = lane & 15;
  const int lhi = lane >> 4;

  f32x4 acc[R][2];
#pragma unroll
  for (int rt = 0; rt < R; ++rt)
#pragma unroll
    for (int ct = 0; ct < 2; ++ct) acc[rt][ct] = (f32x4){0.f, 0.f, 0.f, 0.f};

  auto load_a = [&](f32x4 (&pa)[PF], int t) {
    const float* xs = xbase + t * (BK * D);
#pragma unroll
    for (int s = 0; s < PF; ++s) {
      int idx = tid + s * 512;
      if (idx < CNT) {
        int zl = idx / (8 * D);
        int q = idx - zl * (8 * D);
        pa[s] = *(const f32x4*)(xs + (size_t)zl * DIM + q * 4);
      }
    }
  };

  auto load_b = [&](bf16x8 (&b)[2], int t) {
    const char* wt = wsl + (size_t)t * 32768;
#pragma unroll
    for (int ct = 0; ct < 2; ++ct)
      b[ct] = *(const bf16x8*)(wt + ((lhi * 512 + cb + wave * 32 + ct * 16 + llo) << 4));
  };

  auto stage_write = [&](char* buf, f32x4 (&pa)[PF]) {
#pragma unroll
    for (int s = 0; s < PF; ++s) {
      int idx = tid + s * 512;
      if (idx < CNT) {
        int zl = idx / (8 * D);
        int q = idx - zl * (8 * D);
        if (D == 1) {
          int u0 = q * 4;
          union {
            ushort4v us;
            __bf16 b[4];
          } pk;
#pragma unroll
          for (int e = 0; e < 4; ++e) pk.b[e] = (__bf16)pa[s][e];
          *(ushort4v*)(buf + ((u0 >> 3) * BM + zl) * 16 + (u0 & 7) * 2) = pk.us;
        } else {
#pragma unroll
          for (int e = 0; e < 4; ++e) {
            int cl = q * 4 + e;
            int u = cl / D;
            int i = cl - u * D;
            int r = zl * D + i;
            *(__bf16*)(buf + ((u >> 3) * BM + r) * 16 + (u & 7) * 2) = (__bf16)pa[s][e];
          }
        }
      }
    }
  };

  auto compute = [&](const char* buf, bf16x8 (&b)[2]) {
#pragma unroll
    for (int rt = 0; rt < R; ++rt) {
      bf16x8 af = *(const bf16x8*)(buf + ((lhi * BM + rt * 16 + llo) << 4));
#pragma unroll
      for (int ct = 0; ct < 2; ++ct)
        acc[rt][ct] = __builtin_amdgcn_mfma_f32_16x16x32_bf16(af, b[ct], acc[rt][ct], 0, 0, 0);
    }
  };

  // ---- prologue: 2-deep prefetch; stage tile 0 ----
  f32x4 paE[PF], paO[PF];
  bf16x8 bE[2], bO[2];
  load_a(paE, 0);
  load_b(bE, 0);
  load_a(paO, 1);
  load_b(bO, 1);
  stage_write(smem, paE);  // counted vmcnt: waits only paE(0)
  load_a(paE, 2);
  BAR();

  // ---- main loop: fully unrolled, E/O register parity compile-time ----
#pragma unroll
  for (int tt = 0; tt < NT / 2; ++tt) {
    const int t = 2 * tt;
    compute(smem, bE);
    if (t + 2 < NT) load_b(bE, t + 2);
    stage_write(smem + ABYTES, paO);
    if (t + 3 < NT) load_a(paO, t + 3);
    BAR();
    compute(smem + ABYTES, bO);
    if (t + 3 < NT) load_b(bO, t + 3);
    if (t + 2 < NT) {
      stage_write(smem, paE);
      if (t + 4 < NT) load_a(paE, t + 4);
      BAR();
    }
  }

  // ---- epilogue: C/D layout col=lane&15, row=(lane>>4)*4+reg; fold x2[z] here ----
  float* obase = out + (size_t)z0 * DIM + OFF;
#pragma unroll
  for (int rt = 0; rt < R; ++rt) {
#pragma unroll
    for (int reg = 0; reg < 4; ++reg) {
      int row = rt * 16 + lhi * 4 + reg;
      int z = row / D;
      int i = row - z * D;
      float s = x2[z0 + z];
#pragma unroll
      for (int ct = 0; ct < 2; ++ct) {
        int col = cb + wave * 32 + ct * 16 + llo;
        obase[(size_t)z * DIM + col * D + i] = acc[rt][ct][reg] * s;
      }
    }
  }
}

// One fused kernel: blocks [0,2048) -> l2, [2048,4096) -> l1, [4096,4608) -> l0.
__global__ __launch_bounds__(512, 4) void gemm_fused(const float* __restrict__ x1,
                                                     const float* __restrict__ x2,
                                                     const char* __restrict__ ws,
                                                     float* __restrict__ out) {
  __shared__ __align__(16) char smem[10240];
  int bid = blockIdx.x;
  if (bid < 2048) {
    gemm_body<5, 16, 2048>(bid, x1, x2, ws + 2 * (size_t)WS_L_BYTES, out, smem);
  } else if (bid < 4096) {
    gemm_body<3, 16, 512>(bid - 2048, x1, x2, ws + (size_t)WS_L_BYTES, out, smem);
  } else {
    gemm_body<1, 64, 0>(bid - 4096, x1, x2, ws, out, smem);
  }
}

extern "C" void kernel_launch(void* const* d_in, const int* in_sizes, int n_in,
                              void* d_out, int out_size, void* d_ws, size_t ws_size,
                              hipStream_t stream) {
  const float* x1 = (const float*)d_in[0];
  const float* x2 = (const float*)d_in[1];
  const float* W0 = (const float*)d_in[2];
  const float* W1 = (const float*)d_in[3];
  const float* W2 = (const float*)d_in[4];
  float* out = (float*)d_out;
  char* ws = (char*)d_ws;

  prepack<<<384, 256, 0, stream>>>(W0, W1, W2, ws);
  gemm_fused<<<4608, 512, 0, stream>>>(x1, x2, ws, out);
}